// Round 6
// baseline (1108.651 us; speedup 1.0000x reference)
//
#include <hip/hip_runtime.h>
#include <cstdint>
#include <cstddef>

// ---------------------------------------------------------------------------
// SelfAttention (Flux-style): qkv GEMM + bias -> split q,k,v -> RMSNorm(q,k)
// -> RoPE(q,k) -> flash attention -> out [b,n,dim] fp32.
// b=2, n=2048, dim=2048, h=16, d=128. All MFMA work in bf16 (16x16x32).
//
// R1: XOR-swizzle k_attn LDS (conflicts 1.2e8 -> 1.3e7, attn 347->162us).
// R2: attn VALU diet (fold scale into Q, cvt_pk P-pack, defer-max) + dbuf.
// R3: k_gemm ring-4 LDS + counted vmcnt (159 -> 143us, 717 TF).
// R4: k_attn 8 waves/block, QBLK=128, 16 waves/CU (attn out of top-5).
// R5: k_gemm phase-split: NULL (142us). Diagnosis: LDS-port-bound.
// R6: k_gemm LDS fixes: (a) correct swizzle f(row)=(row>>1)&3 — old (row&3)
//     only spread row&1 over the 16B-granule index G=(4row+slot)%8, leaving
//     2x LDS serialization (9.4e6 conflicts = 574 cy/step on the bottleneck
//     unit); new f makes each 8-lane group hit all 8 granules. (b) ring-2
//     dbuf 64KB -> 2 blocks/CU (TLP covers read/MFMA alternation + the
//     depth-1 vmcnt(0) stage wait). (c) ONE barrier per K-step.
// ---------------------------------------------------------------------------

#define LOG2E 1.4426950408889634f
#define ATT_SCALE 0.08838834764831845f   // 1/sqrt(128)
#define QSCALE (ATT_SCALE * LOG2E)       // folded into Q at normrope

typedef __attribute__((ext_vector_type(8))) __bf16 bf16x8;
typedef __attribute__((ext_vector_type(4))) __bf16 bf16x4;
typedef __attribute__((ext_vector_type(4))) float f32x4;

__device__ __forceinline__ float b2f(unsigned u) {
  u <<= 16;
  return __builtin_bit_cast(float, u);
}
__device__ __forceinline__ unsigned short f2b(float f) {
  unsigned x = __builtin_bit_cast(unsigned, f);
  return (unsigned short)((x + 0x7fffu + ((x >> 16) & 1u)) >> 16);  // RNE
}
// async global->LDS, 16B per lane; lds dest must be wave-uniform base (+lane*16)
__device__ __forceinline__ void gl16(const void* g, void* l) {
  __builtin_amdgcn_global_load_lds((__attribute__((address_space(1))) void*)(g),
                                   (__attribute__((address_space(3))) void*)(l), 16, 0, 0);
}

// ---------------- fp32 -> bf16 convert ----------------
__global__ void k_cvt(const float4* __restrict__ in, ushort4* __restrict__ out, int n4) {
  int i = blockIdx.x * blockDim.x + threadIdx.x;
  int st = gridDim.x * blockDim.x;
  for (; i < n4; i += st) {
    float4 v = in[i];
    ushort4 o;
    o.x = f2b(v.x); o.y = f2b(v.y); o.z = f2b(v.z); o.w = f2b(v.w);
    out[i] = o;
  }
}

// ---------------- QKV GEMM: C[4096][6144] = A[4096][2048] * W[6144][2048]^T + bias ----
// 256x256 tile, BK=32, 512 threads = 8 waves (2M x 4N), each wave 128x64 out
// (8x4 frags of 16x16x32). Ring-2 double-buffer (64KB) -> 2 blocks/CU.
// Per K-step: {vmcnt(0) lgkm(0); barrier; stage(t+1); 12 ds_read_b128;
// setprio(1) 32 MFMA setprio(0)}. Compiler places counted lgkm for frags.
// Swizzle: slot ^= (row>>1)&3 -> conflict-free 8-lane granule groups.
__global__ __launch_bounds__(512, 4) void k_gemm(const unsigned short* __restrict__ A,
                                                 const unsigned short* __restrict__ W,
                                                 const float* __restrict__ bias,
                                                 unsigned short* __restrict__ C) {
  __shared__ __align__(16) unsigned short lds[32768];  // 64KB: 2 x (A[256][32]+B[256][32])
  const int tid = threadIdx.x;
  const int w = tid >> 6, l = tid & 63;
  const int lo = l & 15, hi = l >> 4;
  const int WM = w >> 2, WN = w & 3;
  // bijective XCD swizzle: 384 wgs = 8 XCDs x 48 (two 24-tile M-rows each)
  const int wg = blockIdx.x;
  const int swz = (wg & 7) * 48 + (wg >> 3);
  const int mbase = (swz / 24) * 256, nbase = (swz % 24) * 256;

  // staging geometry: per gl16 round a wave fills 16 rows x 64B; per tile
  // 2 rounds A + 2 rounds B. Source col pre-swizzled so LDS stays linear.
  const int srow = w * 16 + (l >> 2);                        // row in 128-row round
  const int scol = ((l & 3) * 8) ^ (((srow >> 1) & 3) << 3); // involution per row

  auto stage = [&](int t, int buf) {
    unsigned short* Sa = lds + buf * 16384;
    unsigned short* Sb = Sa + 8192;
    const int kt = t * 32;
#pragma unroll
    for (int rd = 0; rd < 2; ++rd) {
      gl16(A + (size_t)(mbase + rd * 128 + srow) * 2048 + kt + scol,
           Sa + (rd * 128 + w * 16) * 32);
      gl16(W + (size_t)(nbase + rd * 128 + srow) * 2048 + kt + scol,
           Sb + (rd * 128 + w * 16) * 32);
    }
  };

  f32x4 acc[8][4] = {};
  stage(0, 0);

  // read-side swizzled element offset: row bits (row>>1)&3 == (lo>>1)&3
  // (i*16, WM*128, WN*64 contribute multiples of 8 to row>>1).
  const int ea = (hi * 8) ^ (((lo >> 1) & 3) << 3);
  for (int t = 0; t < 64; ++t) {
    // vmcnt(0): slot-t staging (issued last step) has landed; lgkmcnt(0) +
    // barrier: all waves' reads of slot t-1 are complete => stage(t+1) into
    // slot (t+1)&1 == (t-1)&1 after the barrier is race-free.
    asm volatile("s_waitcnt vmcnt(0) lgkmcnt(0)" ::: "memory");
    __builtin_amdgcn_sched_barrier(0);
    __builtin_amdgcn_s_barrier();
    __builtin_amdgcn_sched_barrier(0);
    const int cur = t & 1;
    if (t + 1 < 64) stage(t + 1, cur ^ 1);

    const unsigned short* Sa = lds + cur * 16384;
    const unsigned short* Sb = Sa + 8192;
    bf16x8 af[8], bf[4];
#pragma unroll
    for (int i = 0; i < 4; ++i)
      af[i] = *(const bf16x8*)&Sa[(WM * 128 + i * 16 + lo) * 32 + ea];
#pragma unroll
    for (int j = 0; j < 4; ++j)
      bf[j] = *(const bf16x8*)&Sb[(WN * 64 + j * 16 + lo) * 32 + ea];
#pragma unroll
    for (int i = 4; i < 8; ++i)
      af[i] = *(const bf16x8*)&Sa[(WM * 128 + i * 16 + lo) * 32 + ea];

    __builtin_amdgcn_s_setprio(1);
#pragma unroll
    for (int i = 0; i < 8; ++i)
#pragma unroll
      for (int j = 0; j < 4; ++j)
        acc[i][j] = __builtin_amdgcn_mfma_f32_16x16x32_bf16(af[i], bf[j], acc[i][j], 0, 0, 0);
    __builtin_amdgcn_s_setprio(0);
  }

  const int rowb = mbase + WM * 128;
  const int colb = nbase + WN * 64;
#pragma unroll
  for (int j = 0; j < 4; ++j) {
    float bj = bias[colb + j * 16 + lo];
#pragma unroll
    for (int i = 0; i < 8; ++i)
#pragma unroll
      for (int r = 0; r < 4; ++r) {
        int row = rowb + i * 16 + hi * 4 + r;  // C/D: col=lane&15, row=(lane>>4)*4+reg
        C[(size_t)row * 6144 + colb + j * 16 + lo] = f2b(acc[i][j][r] + bj);
      }
  }
}

// ---------------- RMSNorm + RoPE + split ----------------
// qkv[t][o] bf16, o = h*384 + dd*3 + j (j in {q,k,v}). One wave per (b,n,h),
// 4 waves per block; lane handles pair dd = 2l, 2l+1. Writes Q,K,V in
// [b*h][n][128] bf16. Q pre-scaled by ATT_SCALE*LOG2E.
__global__ __launch_bounds__(256) void k_normrope(const unsigned short* __restrict__ qkv,
                                                  const float* __restrict__ qw,
                                                  const float* __restrict__ kw,
                                                  const float* __restrict__ rot,
                                                  unsigned short* __restrict__ Q,
                                                  unsigned short* __restrict__ K,
                                                  unsigned short* __restrict__ V) {
  const int l = threadIdx.x & 63;
  const int idx = blockIdx.x * 4 + (threadIdx.x >> 6);
  const int h = idx & 15;
  const int n = (idx >> 4) & 2047;
  const int b = idx >> 15;
  const unsigned* p = (const unsigned*)(qkv + (size_t)(b * 2048 + n) * 6144 + h * 384 + l * 6);
  unsigned u0 = p[0], u1 = p[1], u2 = p[2];
  float q0 = b2f(u0 & 0xffff), k0 = b2f(u0 >> 16);
  float v0 = b2f(u1 & 0xffff), q1 = b2f(u1 >> 16);
  float k1 = b2f(u2 & 0xffff), v1 = b2f(u2 >> 16);
  (void)v0; (void)v1;
  float sq = q0 * q0 + q1 * q1, sk = k0 * k0 + k1 * k1;
#pragma unroll
  for (int m = 1; m < 64; m <<= 1) {
    sq += __shfl_xor(sq, m, 64);
    sk += __shfl_xor(sk, m, 64);
  }
  float qi = rsqrtf(sq * (1.0f / 128.0f) + 1e-6f) * QSCALE;  // softmax scale folded in
  float ki = rsqrtf(sk * (1.0f / 128.0f) + 1e-6f);
  float2 qwv = *(const float2*)&qw[2 * l];
  float2 kwv = *(const float2*)&kw[2 * l];
  float4 r = *(const float4*)&rot[n * 256 + l * 4];  // [cos, -sin, sin, cos]
  float qn0 = q0 * qi * qwv.x, qn1 = q1 * qi * qwv.y;
  float kn0 = k0 * ki * kwv.x, kn1 = k1 * ki * kwv.y;
  unsigned qo = (unsigned)f2b(r.x * qn0 + r.y * qn1) | ((unsigned)f2b(r.z * qn0 + r.w * qn1) << 16);
  unsigned ko = (unsigned)f2b(r.x * kn0 + r.y * kn1) | ((unsigned)f2b(r.z * kn0 + r.w * kn1) << 16);
  unsigned vo = (u1 & 0xffffu) | (u2 & 0xffff0000u);  // v passthrough (already bf16)
  size_t ob = ((size_t)(b * 16 + h) * 2048 + n) * 128 + 2 * l;
  *(unsigned*)(Q + ob) = qo;
  *(unsigned*)(K + ob) = ko;
  *(unsigned*)(V + ob) = vo;
}

// ---------------- V transpose: [bh][n][128] -> [bh][128][n] ----------------
__global__ __launch_bounds__(256) void k_transpose(const unsigned short* __restrict__ V,
                                                   unsigned short* __restrict__ Vt) {
  __shared__ unsigned short tile[64 * 66];
  const int t = threadIdx.x;
  const int d0 = blockIdx.x * 64;
  const int n0 = blockIdx.y * 64;
  const int bh = blockIdx.z;
#pragma unroll
  for (int s = t; s < 512; s += 256) {
    int nr = s >> 3, c8 = (s & 7) * 8;
    uint4 vv = *(const uint4*)(V + ((size_t)bh * 2048 + n0 + nr) * 128 + d0 + c8);
    unsigned* tp = (unsigned*)&tile[nr * 66 + c8];
    tp[0] = vv.x; tp[1] = vv.y; tp[2] = vv.z; tp[3] = vv.w;
  }
  __syncthreads();
#pragma unroll
  for (int s = t; s < 512; s += 256) {
    int dr = s >> 3, n8 = (s & 7) * 8;
    unsigned short e[8];
#pragma unroll
    for (int j = 0; j < 8; ++j) e[j] = tile[(n8 + j) * 66 + dr];
    uint4 o;
    o.x = e[0] | ((unsigned)e[1] << 16);
    o.y = e[2] | ((unsigned)e[3] << 16);
    o.z = e[4] | ((unsigned)e[5] << 16);
    o.w = e[6] | ((unsigned)e[7] << 16);
    *(uint4*)(Vt + ((size_t)bh * 128 + d0 + dr) * 2048 + n0 + n8) = o;
  }
}

// ---------------- flash attention ----------------
// R4: 8 waves (512 thr), each owns 16 q-rows (QBLK=128). KV tiles of 64,
// double-buffered, staged cooperatively by all 8 waves (4 gl16/thread).
// S^T = K*Q^T (D row=kv, col=q) so row stats reduce via shfl_xor(16,32);
// P^T written to per-wave LDS as Ps[q][kv]; O^T = V^T * P^T in 8 frags.
// All LDS tiles XOR-swizzled: element_off_in_row ^= ((row & 7) << 3).
// Q arrives pre-scaled by ATT_SCALE*LOG2E, so S is already in log2 units.
// LDS = 2*(16KB K + 16KB Vt) + 8*2KB Ps = 80KB -> 2 blocks/CU, 16 waves/CU.
__global__ __launch_bounds__(512, 4) void k_attn(const unsigned short* __restrict__ Q,
                                                 const unsigned short* __restrict__ K,
                                                 const unsigned short* __restrict__ Vt,
                                                 float* __restrict__ out) {
  __shared__ __align__(16) unsigned short lds[40960];  // 80KB
  unsigned short* Ps = lds + 32768;                    // 8 waves x [16][64]
  const int tid = threadIdx.x;
  const int w = tid >> 6, l = tid & 63;
  const int lo = l & 15, hi = l >> 4;
  const int swz = (lo & 7) << 3;       // read-side XOR for row = ...+lo tiles
  const int qt = blockIdx.x, bh = blockIdx.y;
  const unsigned short* Qb = Q + (size_t)bh * 2048 * 128;
  const unsigned short* Kb = K + (size_t)bh * 2048 * 128;
  const unsigned short* Vb = Vt + (size_t)bh * 128 * 2048;
  unsigned short* Psw = Ps + w * 1024;

  bf16x8 qf[4];
  const int qrow = qt * 128 + w * 16 + lo;
#pragma unroll
  for (int dk = 0; dk < 4; ++dk)
    qf[dk] = *(const bf16x8*)&Qb[(size_t)qrow * 128 + dk * 32 + hi * 8];

  f32x4 Oacc[8] = {};
  float m_run = -__builtin_inff(), l_run = 0.0f;

  // Running per-thread source pointers. Swizzle XOR constants are
  // tile-invariant: tile (t*64) and round (r*32 / r*64) row offsets are
  // multiples of 8, so row&7 depends only on the per-thread base row.
  const int krow0 = w * 4 + hi;             // K row within 32-row round
  const int vrow0 = w * 8 + (l >> 3);       // Vt row within 64-row round
  const unsigned short* kp = Kb + (size_t)krow0 * 128 + ((lo * 8) ^ ((krow0 & 7) << 3));
  const unsigned short* vp = Vb + (size_t)vrow0 * 2048 + (((l & 7) * 8) ^ ((vrow0 & 7) << 3));

  // stage KV tile t into buffer b: K[64][128] in 2 rounds of 32 rows,
  // Vt[128->covered 64 cols][...] i.e. Vts[128][64] in 2 rounds of 64 rows.
  auto stage = [&](int t, int b) {
    unsigned short* Ksb = lds + b * 16384;
    unsigned short* Vtsb = Ksb + 8192;
#pragma unroll
    for (int r = 0; r < 2; ++r) {
      gl16(kp + (size_t)t * 8192 + r * 4096,            // 64*128 per tile, 32*128 per round
           Ksb + (r * 32 + w * 4) * 128);
      gl16(vp + (size_t)r * 131072 + t * 64,            // 64 rows * 2048 per round
           Vtsb + (r * 64 + w * 8) * 64);
    }
  };

  stage(0, 0);
  int cur = 0;
  for (int t = 0; t < 32; ++t) {
    // __syncthreads drains vmcnt(0)+lgkmcnt(0): the stage issued last
    // iteration has had a full compute phase of slack before this wait,
    // and all waves' reads of buffer cur^1 (iter t-1) are complete.
    __syncthreads();
    if (t + 1 < 32) stage(t + 1, cur ^ 1);
    const unsigned short* Ks = lds + cur * 16384;
    const unsigned short* Vts = Ks + 8192;

    f32x4 S[4] = {};
#pragma unroll
    for (int kf = 0; kf < 4; ++kf)
#pragma unroll
      for (int dk = 0; dk < 4; ++dk)
        S[kf] = __builtin_amdgcn_mfma_f32_16x16x32_bf16(
            *(const bf16x8*)&Ks[(kf * 16 + lo) * 128 + ((dk * 32 + hi * 8) ^ swz)],
            qf[dk], S[kf], 0, 0, 0);

    // row max (tree; S already in log2 units)
    float m01, m23, mt;
    m01 = fmaxf(fmaxf(S[0][0], S[0][1]), fmaxf(S[0][2], S[0][3]));
    m23 = fmaxf(fmaxf(S[1][0], S[1][1]), fmaxf(S[1][2], S[1][3]));
    mt = fmaxf(m01, m23);
    m01 = fmaxf(fmaxf(S[2][0], S[2][1]), fmaxf(S[2][2], S[2][3]));
    m23 = fmaxf(fmaxf(S[3][0], S[3][1]), fmaxf(S[3][2], S[3][3]));
    mt = fmaxf(mt, fmaxf(m01, m23));
    mt = fmaxf(mt, __shfl_xor(mt, 16, 64));
    mt = fmaxf(mt, __shfl_xor(mt, 32, 64));

    // T13 defer-max: skip rescale when the new tile max is within 8 of the
    // running max (P bounded by 2^8; f32 accum has headroom).
    const bool defer = __all(mt <= m_run + 8.0f);
    float m_new = m_run, alpha = 1.0f;
    if (!defer) {
      m_new = fmaxf(m_run, mt);
      alpha = exp2f(m_run - m_new);
    }

    float p[4][4];
    float ls = 0.0f;
#pragma unroll
    for (int kf = 0; kf < 4; ++kf)
#pragma unroll
      for (int r = 0; r < 4; ++r) {
        p[kf][r] = exp2f(S[kf][r] - m_new);
        ls += p[kf][r];
      }
    ls += __shfl_xor(ls, 16, 64);
    ls += __shfl_xor(ls, 32, 64);

    // pack P to bf16 via compiler casts (v_cvt_pk_bf16_f32)
#pragma unroll
    for (int kf = 0; kf < 4; ++kf) {
      bf16x4 pk;
      pk[0] = (__bf16)p[kf][0]; pk[1] = (__bf16)p[kf][1];
      pk[2] = (__bf16)p[kf][2]; pk[3] = (__bf16)p[kf][3];
      // Ps[q=lo][kv=kf*16+hi*4 .. +3], swizzled by row q (same-wave buffer).
      *(bf16x4*)&Psw[lo * 64 + ((kf * 16 + hi * 4) ^ swz)] = pk;
    }

    if (!defer) {
#pragma unroll
      for (int df = 0; df < 8; ++df) {
        Oacc[df][0] *= alpha; Oacc[df][1] *= alpha;
        Oacc[df][2] *= alpha; Oacc[df][3] *= alpha;
      }
      l_run = l_run * alpha + ls;
      m_run = m_new;
    } else {
      l_run += ls;
    }

    const bf16x8 pb0 = *(const bf16x8*)&Psw[lo * 64 + ((hi * 8) ^ swz)];
    const bf16x8 pb1 = *(const bf16x8*)&Psw[lo * 64 + ((32 + hi * 8) ^ swz)];
#pragma unroll
    for (int df = 0; df < 8; ++df) {
      Oacc[df] = __builtin_amdgcn_mfma_f32_16x16x32_bf16(
          *(const bf16x8*)&Vts[(df * 16 + lo) * 64 + ((hi * 8) ^ swz)], pb0, Oacc[df], 0, 0, 0);
      Oacc[df] = __builtin_amdgcn_mfma_f32_16x16x32_bf16(
          *(const bf16x8*)&Vts[(df * 16 + lo) * 64 + ((32 + hi * 8) ^ swz)], pb1, Oacc[df], 0, 0, 0);
    }
    cur ^= 1;
  }

  const float inv = 1.0f / l_run;  // valid for q = lo (replicated across hi groups)
  __syncthreads();                 // done with K/V bufs; reuse as fp32 O staging
  float* Ot = ((float*)lds) + w * 2048;  // [16 q][128 dv] per wave (8x8KB = 64KB)
#pragma unroll
  for (int df = 0; df < 8; ++df)
#pragma unroll
    for (int r = 0; r < 4; ++r)
      Ot[lo * 128 + df * 16 + hi * 4 + r] = Oacc[df][r] * inv;
  const int b = bh >> 4, h = bh & 15;
  const int q2 = l >> 2, c = (l & 3) * 32;
  float* op = out + ((size_t)(b * 2048 + qt * 128 + w * 16 + q2) * 2048 + h * 128 + c);
#pragma unroll
  for (int u = 0; u < 8; ++u)
    *(float4*)&op[u * 4] = *(const float4*)&Ot[q2 * 128 + c + u * 4];
}

// ---------------------------------------------------------------------------
extern "C" void kernel_launch(void* const* d_in, const int* in_sizes, int n_in,
                              void* d_out, int out_size, void* d_ws, size_t ws_size,
                              hipStream_t stream) {
  (void)in_sizes; (void)n_in; (void)out_size; (void)ws_size;
  const float* x = (const float*)d_in[0];
  const float* qkv_w = (const float*)d_in[1];
  const float* qkv_b = (const float*)d_in[2];
  const float* q_norm_w = (const float*)d_in[3];
  const float* k_norm_w = (const float*)d_in[4];
  const float* rot = (const float*)d_in[5];
  float* out = (float*)d_out;
  char* ws = (char*)d_ws;
  // ws layout (bytes): xb 16MB | wb 24MB | qkv 48MB | Q 16MB | K 16MB | V 16MB
  // Vt aliases xb region (dead after GEMM). Total required: ~136 MiB.
  unsigned short* xb  = (unsigned short*)(ws);
  unsigned short* wb  = (unsigned short*)(ws + 16777216);
  unsigned short* qkv = (unsigned short*)(ws + 41943040);
  unsigned short* Qb  = (unsigned short*)(ws + 92274688);
  unsigned short* Kb  = (unsigned short*)(ws + 109051904);
  unsigned short* Vb  = (unsigned short*)(ws + 125829120);
  unsigned short* Vtb = (unsigned short*)(ws);  // alias

  hipLaunchKernelGGL(k_cvt, dim3(1024), dim3(256), 0, stream,
                     (const float4*)x, (ushort4*)xb, 8388608 / 4);
  hipLaunchKernelGGL(k_cvt, dim3(1024), dim3(256), 0, stream,
                     (const float4*)qkv_w, (ushort4*)wb, 12582912 / 4);
  hipLaunchKernelGGL(k_gemm, dim3(384), dim3(512), 0, stream, xb, wb, qkv_b, qkv);
  hipLaunchKernelGGL(k_normrope, dim3(16384), dim3(256), 0, stream,
                     qkv, q_norm_w, k_norm_w, rot, Qb, Kb, Vb);
  hipLaunchKernelGGL(k_transpose, dim3(2, 32, 32), dim3(256), 0, stream, Vb, Vtb);
  hipLaunchKernelGGL(k_attn, dim3(16, 32), dim3(512), 0, stream, Qb, Kb, Vtb, out);
}

// Round 7
// 304.244 us; speedup vs baseline: 3.6440x; 3.6440x over previous
//
#include <hip/hip_runtime.h>
#include <cstdint>
#include <cstddef>

// ---------------------------------------------------------------------------
// SelfAttention (Flux-style): qkv GEMM + bias -> split q,k,v -> RMSNorm(q,k)
// -> RoPE(q,k) -> flash attention -> out [b,n,dim] fp32.
// b=2, n=2048, dim=2048, h=16, d=128. All MFMA work in bf16 (16x16x32).
//
// R1: XOR-swizzle k_attn LDS (conflicts 1.2e8 -> 1.3e7, attn 347->162us).
// R2: attn VALU diet (fold scale into Q, cvt_pk P-pack, defer-max) + dbuf.
// R3: k_gemm ring-4 LDS + counted vmcnt (159 -> 143us, 717 TF).
// R4: k_attn 8 waves/block, QBLK=128, 16 waves/CU (attn out of top-5).
// R5: k_gemm phase-split: NULL. Diagnosis: LDS-port-bound + makespan.
// R6: launch_bounds(512,4) reg-cap -> scratch spill (FETCH 1.8GB, 970us).
//     BUT: swizzle f(row)=(row>>1)&3 verified conflict-free (PMC=0.0).
// R7: k_gemm BM=256 x BN=384 tiles -> grid 16x16=256 = EXACTLY 1 block/CU,
//     single pass, no tail (was 384 blocks = 2 uneven passes, 75% util).
//     Ring-3 x 40KB = 120KB LDS, depth-2 prefetch, counted vmcnt(5).
//     Per wave: 14 ds_read_b128 per 48 MFMA (0.29 reads/MFMA, was 0.375).
//     Conflict-free swizzle kept. launch_bounds(512,2) (R3-proven: no spill).
// ---------------------------------------------------------------------------

#define LOG2E 1.4426950408889634f
#define ATT_SCALE 0.08838834764831845f   // 1/sqrt(128)
#define QSCALE (ATT_SCALE * LOG2E)       // folded into Q at normrope

typedef __attribute__((ext_vector_type(8))) __bf16 bf16x8;
typedef __attribute__((ext_vector_type(4))) __bf16 bf16x4;
typedef __attribute__((ext_vector_type(4))) float f32x4;

__device__ __forceinline__ float b2f(unsigned u) {
  u <<= 16;
  return __builtin_bit_cast(float, u);
}
__device__ __forceinline__ unsigned short f2b(float f) {
  unsigned x = __builtin_bit_cast(unsigned, f);
  return (unsigned short)((x + 0x7fffu + ((x >> 16) & 1u)) >> 16);  // RNE
}
// async global->LDS, 16B per lane; lds dest must be wave-uniform base (+lane*16)
__device__ __forceinline__ void gl16(const void* g, void* l) {
  __builtin_amdgcn_global_load_lds((__attribute__((address_space(1))) void*)(g),
                                   (__attribute__((address_space(3))) void*)(l), 16, 0, 0);
}

// ---------------- fp32 -> bf16 convert ----------------
__global__ void k_cvt(const float4* __restrict__ in, ushort4* __restrict__ out, int n4) {
  int i = blockIdx.x * blockDim.x + threadIdx.x;
  int st = gridDim.x * blockDim.x;
  for (; i < n4; i += st) {
    float4 v = in[i];
    ushort4 o;
    o.x = f2b(v.x); o.y = f2b(v.y); o.z = f2b(v.z); o.w = f2b(v.w);
    out[i] = o;
  }
}

// ---------------- QKV GEMM: C[4096][6144] = A[4096][2048] * W[6144][2048]^T + bias ----
// 256x384 tile, BK=32, 512 threads = 8 waves (2M x 4N); wave = 128x96 out
// (8x6 frags of 16x16x32, 48 MFMA/step). Grid 16x16 = 256 = 1 block/CU.
// Ring-3 LDS slots of 40KB (A 16KB + B 24KB); stage(t+2) while computing t.
// Per step: {vmcnt(5) lgkm(0); barrier; stage; 14 ds_read_b128; 48 MFMA}.
// Swizzle slot ^= (row>>1)&3: 16B-granule G=(4row+slot)%8 uniform over each
// 8-lane group -> conflict-free (verified R6: SQ_LDS_BANK_CONFLICT = 0).
__global__ __launch_bounds__(512, 2) void k_gemm(const unsigned short* __restrict__ A,
                                                 const unsigned short* __restrict__ W,
                                                 const float* __restrict__ bias,
                                                 unsigned short* __restrict__ C) {
  __shared__ __align__(16) unsigned short lds[61440];  // 120KB: 3 x (A[256][32] + B[384][32])
  const int tid = threadIdx.x;
  const int w = tid >> 6, l = tid & 63;
  const int lo = l & 15, hi = l >> 4;
  const int WM = w >> 2, WN = w & 3;
  // bijective XCD swizzle: 256 wgs = 8 XCDs x 32 (two 16-tile n-rows each)
  const int wg = blockIdx.x;
  const int swz = (wg & 7) * 32 + (wg >> 3);
  const int mbase = (swz >> 4) * 256, nbase = (swz & 15) * 384;

  // staging: per gl16 round a wave covers 16 rows x 64B (512 thr = 128 rows).
  // A = 2 rounds, B = 3 rounds. Source col pre-swizzled; LDS dest linear.
  const int srow = w * 16 + (l >> 2);                        // row in 128-row round
  const int scol = ((l & 3) * 8) ^ (((srow >> 1) & 3) << 3); // involution per row

  auto stage = [&](int t, int slot) {
    unsigned short* Sa = lds + slot * 20480;
    unsigned short* Sb = Sa + 8192;
    const int kt = t * 32;
#pragma unroll
    for (int rd = 0; rd < 2; ++rd)
      gl16(A + (size_t)(mbase + rd * 128 + srow) * 2048 + kt + scol,
           Sa + (rd * 128 + w * 16) * 32);
#pragma unroll
    for (int rd = 0; rd < 3; ++rd)
      gl16(W + (size_t)(nbase + rd * 128 + srow) * 2048 + kt + scol,
           Sb + (rd * 128 + w * 16) * 32);
  };

  f32x4 acc[8][6] = {};
  stage(0, 0);
  stage(1, 1);   // 10 gl16 in flight

  // read-side swizzled element offset: all row terms (i*16, WM*128, WN*96)
  // are multiples of 16, so (row>>1)&3 == (lo>>1)&3.
  const int ea = (hi * 8) ^ (((lo >> 1) & 3) << 3);
  int cur = 0;
  for (int t = 0; t < 64; ++t) {
    // vmcnt(5): drain slot-t's 5 loads (issued at t-2); slot-(t+1)'s 5 stay
    // in flight. lgkmcnt(0)+barrier: all waves' reads of slot t-1 are done
    // => stage(t+2) into slot (t-1)%3 after the barrier is race-free.
    if (t < 63) asm volatile("s_waitcnt vmcnt(5) lgkmcnt(0)" ::: "memory");
    else        asm volatile("s_waitcnt vmcnt(0) lgkmcnt(0)" ::: "memory");
    __builtin_amdgcn_sched_barrier(0);
    __builtin_amdgcn_s_barrier();
    __builtin_amdgcn_sched_barrier(0);
    if (t + 2 < 64) {
      int sn = cur + 2; if (sn >= 3) sn -= 3;
      stage(t + 2, sn);
    }

    const unsigned short* Sa = lds + cur * 20480;
    const unsigned short* Sb = Sa + 8192;
    bf16x8 af[8], bf[6];
#pragma unroll
    for (int i = 0; i < 8; ++i)
      af[i] = *(const bf16x8*)&Sa[(WM * 128 + i * 16 + lo) * 32 + ea];
#pragma unroll
    for (int j = 0; j < 6; ++j)
      bf[j] = *(const bf16x8*)&Sb[(WN * 96 + j * 16 + lo) * 32 + ea];

    __builtin_amdgcn_s_setprio(1);
#pragma unroll
    for (int i = 0; i < 8; ++i)
#pragma unroll
      for (int j = 0; j < 6; ++j)
        acc[i][j] = __builtin_amdgcn_mfma_f32_16x16x32_bf16(af[i], bf[j], acc[i][j], 0, 0, 0);
    __builtin_amdgcn_s_setprio(0);
    cur = (cur == 2) ? 0 : cur + 1;
  }

  const int rowb = mbase + WM * 128;
  const int colb = nbase + WN * 96;
#pragma unroll
  for (int j = 0; j < 6; ++j) {
    float bj = bias[colb + j * 16 + lo];
#pragma unroll
    for (int i = 0; i < 8; ++i)
#pragma unroll
      for (int r = 0; r < 4; ++r) {
        int row = rowb + i * 16 + hi * 4 + r;  // C/D: col=lane&15, row=(lane>>4)*4+reg
        C[(size_t)row * 6144 + colb + j * 16 + lo] = f2b(acc[i][j][r] + bj);
      }
  }
}

// ---------------- RMSNorm + RoPE + split ----------------
// qkv[t][o] bf16, o = h*384 + dd*3 + j (j in {q,k,v}). One wave per (b,n,h),
// 4 waves per block; lane handles pair dd = 2l, 2l+1. Writes Q,K,V in
// [b*h][n][128] bf16. Q pre-scaled by ATT_SCALE*LOG2E.
__global__ __launch_bounds__(256) void k_normrope(const unsigned short* __restrict__ qkv,
                                                  const float* __restrict__ qw,
                                                  const float* __restrict__ kw,
                                                  const float* __restrict__ rot,
                                                  unsigned short* __restrict__ Q,
                                                  unsigned short* __restrict__ K,
                                                  unsigned short* __restrict__ V) {
  const int l = threadIdx.x & 63;
  const int idx = blockIdx.x * 4 + (threadIdx.x >> 6);
  const int h = idx & 15;
  const int n = (idx >> 4) & 2047;
  const int b = idx >> 15;
  const unsigned* p = (const unsigned*)(qkv + (size_t)(b * 2048 + n) * 6144 + h * 384 + l * 6);
  unsigned u0 = p[0], u1 = p[1], u2 = p[2];
  float q0 = b2f(u0 & 0xffff), k0 = b2f(u0 >> 16);
  float v0 = b2f(u1 & 0xffff), q1 = b2f(u1 >> 16);
  float k1 = b2f(u2 & 0xffff), v1 = b2f(u2 >> 16);
  (void)v0; (void)v1;
  float sq = q0 * q0 + q1 * q1, sk = k0 * k0 + k1 * k1;
#pragma unroll
  for (int m = 1; m < 64; m <<= 1) {
    sq += __shfl_xor(sq, m, 64);
    sk += __shfl_xor(sk, m, 64);
  }
  float qi = rsqrtf(sq * (1.0f / 128.0f) + 1e-6f) * QSCALE;  // softmax scale folded in
  float ki = rsqrtf(sk * (1.0f / 128.0f) + 1e-6f);
  float2 qwv = *(const float2*)&qw[2 * l];
  float2 kwv = *(const float2*)&kw[2 * l];
  float4 r = *(const float4*)&rot[n * 256 + l * 4];  // [cos, -sin, sin, cos]
  float qn0 = q0 * qi * qwv.x, qn1 = q1 * qi * qwv.y;
  float kn0 = k0 * ki * kwv.x, kn1 = k1 * ki * kwv.y;
  unsigned qo = (unsigned)f2b(r.x * qn0 + r.y * qn1) | ((unsigned)f2b(r.z * qn0 + r.w * qn1) << 16);
  unsigned ko = (unsigned)f2b(r.x * kn0 + r.y * kn1) | ((unsigned)f2b(r.z * kn0 + r.w * kn1) << 16);
  unsigned vo = (u1 & 0xffffu) | (u2 & 0xffff0000u);  // v passthrough (already bf16)
  size_t ob = ((size_t)(b * 16 + h) * 2048 + n) * 128 + 2 * l;
  *(unsigned*)(Q + ob) = qo;
  *(unsigned*)(K + ob) = ko;
  *(unsigned*)(V + ob) = vo;
}

// ---------------- V transpose: [bh][n][128] -> [bh][128][n] ----------------
__global__ __launch_bounds__(256) void k_transpose(const unsigned short* __restrict__ V,
                                                   unsigned short* __restrict__ Vt) {
  __shared__ unsigned short tile[64 * 66];
  const int t = threadIdx.x;
  const int d0 = blockIdx.x * 64;
  const int n0 = blockIdx.y * 64;
  const int bh = blockIdx.z;
#pragma unroll
  for (int s = t; s < 512; s += 256) {
    int nr = s >> 3, c8 = (s & 7) * 8;
    uint4 vv = *(const uint4*)(V + ((size_t)bh * 2048 + n0 + nr) * 128 + d0 + c8);
    unsigned* tp = (unsigned*)&tile[nr * 66 + c8];
    tp[0] = vv.x; tp[1] = vv.y; tp[2] = vv.z; tp[3] = vv.w;
  }
  __syncthreads();
#pragma unroll
  for (int s = t; s < 512; s += 256) {
    int dr = s >> 3, n8 = (s & 7) * 8;
    unsigned short e[8];
#pragma unroll
    for (int j = 0; j < 8; ++j) e[j] = tile[(n8 + j) * 66 + dr];
    uint4 o;
    o.x = e[0] | ((unsigned)e[1] << 16);
    o.y = e[2] | ((unsigned)e[3] << 16);
    o.z = e[4] | ((unsigned)e[5] << 16);
    o.w = e[6] | ((unsigned)e[7] << 16);
    *(uint4*)(Vt + ((size_t)bh * 128 + d0 + dr) * 2048 + n0 + n8) = o;
  }
}

// ---------------- flash attention ----------------
// R4: 8 waves (512 thr), each owns 16 q-rows (QBLK=128). KV tiles of 64,
// double-buffered, staged cooperatively by all 8 waves (4 gl16/thread).
// S^T = K*Q^T (D row=kv, col=q) so row stats reduce via shfl_xor(16,32);
// P^T written to per-wave LDS as Ps[q][kv]; O^T = V^T * P^T in 8 frags.
// All LDS tiles XOR-swizzled: element_off_in_row ^= ((row & 7) << 3).
// Q arrives pre-scaled by ATT_SCALE*LOG2E, so S is already in log2 units.
// LDS = 2*(16KB K + 16KB Vt) + 8*2KB Ps = 80KB -> 2 blocks/CU, 16 waves/CU.
__global__ __launch_bounds__(512, 4) void k_attn(const unsigned short* __restrict__ Q,
                                                 const unsigned short* __restrict__ K,
                                                 const unsigned short* __restrict__ Vt,
                                                 float* __restrict__ out) {
  __shared__ __align__(16) unsigned short lds[40960];  // 80KB
  unsigned short* Ps = lds + 32768;                    // 8 waves x [16][64]
  const int tid = threadIdx.x;
  const int w = tid >> 6, l = tid & 63;
  const int lo = l & 15, hi = l >> 4;
  const int swz = (lo & 7) << 3;       // read-side XOR for row = ...+lo tiles
  const int qt = blockIdx.x, bh = blockIdx.y;
  const unsigned short* Qb = Q + (size_t)bh * 2048 * 128;
  const unsigned short* Kb = K + (size_t)bh * 2048 * 128;
  const unsigned short* Vb = Vt + (size_t)bh * 128 * 2048;
  unsigned short* Psw = Ps + w * 1024;

  bf16x8 qf[4];
  const int qrow = qt * 128 + w * 16 + lo;
#pragma unroll
  for (int dk = 0; dk < 4; ++dk)
    qf[dk] = *(const bf16x8*)&Qb[(size_t)qrow * 128 + dk * 32 + hi * 8];

  f32x4 Oacc[8] = {};
  float m_run = -__builtin_inff(), l_run = 0.0f;

  // Running per-thread source pointers. Swizzle XOR constants are
  // tile-invariant: tile (t*64) and round (r*32 / r*64) row offsets are
  // multiples of 8, so row&7 depends only on the per-thread base row.
  const int krow0 = w * 4 + hi;             // K row within 32-row round
  const int vrow0 = w * 8 + (l >> 3);       // Vt row within 64-row round
  const unsigned short* kp = Kb + (size_t)krow0 * 128 + ((lo * 8) ^ ((krow0 & 7) << 3));
  const unsigned short* vp = Vb + (size_t)vrow0 * 2048 + (((l & 7) * 8) ^ ((vrow0 & 7) << 3));

  // stage KV tile t into buffer b: K[64][128] in 2 rounds of 32 rows,
  // Vt[128->covered 64 cols][...] i.e. Vts[128][64] in 2 rounds of 64 rows.
  auto stage = [&](int t, int b) {
    unsigned short* Ksb = lds + b * 16384;
    unsigned short* Vtsb = Ksb + 8192;
#pragma unroll
    for (int r = 0; r < 2; ++r) {
      gl16(kp + (size_t)t * 8192 + r * 4096,            // 64*128 per tile, 32*128 per round
           Ksb + (r * 32 + w * 4) * 128);
      gl16(vp + (size_t)r * 131072 + t * 64,            // 64 rows * 2048 per round
           Vtsb + (r * 64 + w * 8) * 64);
    }
  };

  stage(0, 0);
  int cur = 0;
  for (int t = 0; t < 32; ++t) {
    // __syncthreads drains vmcnt(0)+lgkmcnt(0): the stage issued last
    // iteration has had a full compute phase of slack before this wait,
    // and all waves' reads of buffer cur^1 (iter t-1) are complete.
    __syncthreads();
    if (t + 1 < 32) stage(t + 1, cur ^ 1);
    const unsigned short* Ks = lds + cur * 16384;
    const unsigned short* Vts = Ks + 8192;

    f32x4 S[4] = {};
#pragma unroll
    for (int kf = 0; kf < 4; ++kf)
#pragma unroll
      for (int dk = 0; dk < 4; ++dk)
        S[kf] = __builtin_amdgcn_mfma_f32_16x16x32_bf16(
            *(const bf16x8*)&Ks[(kf * 16 + lo) * 128 + ((dk * 32 + hi * 8) ^ swz)],
            qf[dk], S[kf], 0, 0, 0);

    // row max (tree; S already in log2 units)
    float m01, m23, mt;
    m01 = fmaxf(fmaxf(S[0][0], S[0][1]), fmaxf(S[0][2], S[0][3]));
    m23 = fmaxf(fmaxf(S[1][0], S[1][1]), fmaxf(S[1][2], S[1][3]));
    mt = fmaxf(m01, m23);
    m01 = fmaxf(fmaxf(S[2][0], S[2][1]), fmaxf(S[2][2], S[2][3]));
    m23 = fmaxf(fmaxf(S[3][0], S[3][1]), fmaxf(S[3][2], S[3][3]));
    mt = fmaxf(mt, fmaxf(m01, m23));
    mt = fmaxf(mt, __shfl_xor(mt, 16, 64));
    mt = fmaxf(mt, __shfl_xor(mt, 32, 64));

    // T13 defer-max: skip rescale when the new tile max is within 8 of the
    // running max (P bounded by 2^8; f32 accum has headroom).
    const bool defer = __all(mt <= m_run + 8.0f);
    float m_new = m_run, alpha = 1.0f;
    if (!defer) {
      m_new = fmaxf(m_run, mt);
      alpha = exp2f(m_run - m_new);
    }

    float p[4][4];
    float ls = 0.0f;
#pragma unroll
    for (int kf = 0; kf < 4; ++kf)
#pragma unroll
      for (int r = 0; r < 4; ++r) {
        p[kf][r] = exp2f(S[kf][r] - m_new);
        ls += p[kf][r];
      }
    ls += __shfl_xor(ls, 16, 64);
    ls += __shfl_xor(ls, 32, 64);

    // pack P to bf16 via compiler casts (v_cvt_pk_bf16_f32)
#pragma unroll
    for (int kf = 0; kf < 4; ++kf) {
      bf16x4 pk;
      pk[0] = (__bf16)p[kf][0]; pk[1] = (__bf16)p[kf][1];
      pk[2] = (__bf16)p[kf][2]; pk[3] = (__bf16)p[kf][3];
      // Ps[q=lo][kv=kf*16+hi*4 .. +3], swizzled by row q (same-wave buffer).
      *(bf16x4*)&Psw[lo * 64 + ((kf * 16 + hi * 4) ^ swz)] = pk;
    }

    if (!defer) {
#pragma unroll
      for (int df = 0; df < 8; ++df) {
        Oacc[df][0] *= alpha; Oacc[df][1] *= alpha;
        Oacc[df][2] *= alpha; Oacc[df][3] *= alpha;
      }
      l_run = l_run * alpha + ls;
      m_run = m_new;
    } else {
      l_run += ls;
    }

    const bf16x8 pb0 = *(const bf16x8*)&Psw[lo * 64 + ((hi * 8) ^ swz)];
    const bf16x8 pb1 = *(const bf16x8*)&Psw[lo * 64 + ((32 + hi * 8) ^ swz)];
#pragma unroll
    for (int df = 0; df < 8; ++df) {
      Oacc[df] = __builtin_amdgcn_mfma_f32_16x16x32_bf16(
          *(const bf16x8*)&Vts[(df * 16 + lo) * 64 + ((hi * 8) ^ swz)], pb0, Oacc[df], 0, 0, 0);
      Oacc[df] = __builtin_amdgcn_mfma_f32_16x16x32_bf16(
          *(const bf16x8*)&Vts[(df * 16 + lo) * 64 + ((32 + hi * 8) ^ swz)], pb1, Oacc[df], 0, 0, 0);
    }
    cur ^= 1;
  }

  const float inv = 1.0f / l_run;  // valid for q = lo (replicated across hi groups)
  __syncthreads();                 // done with K/V bufs; reuse as fp32 O staging
  float* Ot = ((float*)lds) + w * 2048;  // [16 q][128 dv] per wave (8x8KB = 64KB)
#pragma unroll
  for (int df = 0; df < 8; ++df)
#pragma unroll
    for (int r = 0; r < 4; ++r)
      Ot[lo * 128 + df * 16 + hi * 4 + r] = Oacc[df][r] * inv;
  const int b = bh >> 4, h = bh & 15;
  const int q2 = l >> 2, c = (l & 3) * 32;
  float* op = out + ((size_t)(b * 2048 + qt * 128 + w * 16 + q2) * 2048 + h * 128 + c);
#pragma unroll
  for (int u = 0; u < 8; ++u)
    *(float4*)&op[u * 4] = *(const float4*)&Ot[q2 * 128 + c + u * 4];
}

// ---------------------------------------------------------------------------
extern "C" void kernel_launch(void* const* d_in, const int* in_sizes, int n_in,
                              void* d_out, int out_size, void* d_ws, size_t ws_size,
                              hipStream_t stream) {
  (void)in_sizes; (void)n_in; (void)out_size; (void)ws_size;
  const float* x = (const float*)d_in[0];
  const float* qkv_w = (const float*)d_in[1];
  const float* qkv_b = (const float*)d_in[2];
  const float* q_norm_w = (const float*)d_in[3];
  const float* k_norm_w = (const float*)d_in[4];
  const float* rot = (const float*)d_in[5];
  float* out = (float*)d_out;
  char* ws = (char*)d_ws;
  // ws layout (bytes): xb 16MB | wb 24MB | qkv 48MB | Q 16MB | K 16MB | V 16MB
  // Vt aliases xb region (dead after GEMM). Total required: ~136 MiB.
  unsigned short* xb  = (unsigned short*)(ws);
  unsigned short* wb  = (unsigned short*)(ws + 16777216);
  unsigned short* qkv = (unsigned short*)(ws + 41943040);
  unsigned short* Qb  = (unsigned short*)(ws + 92274688);
  unsigned short* Kb  = (unsigned short*)(ws + 109051904);
  unsigned short* Vb  = (unsigned short*)(ws + 125829120);
  unsigned short* Vtb = (unsigned short*)(ws);  // alias

  hipLaunchKernelGGL(k_cvt, dim3(1024), dim3(256), 0, stream,
                     (const float4*)x, (ushort4*)xb, 8388608 / 4);
  hipLaunchKernelGGL(k_cvt, dim3(1024), dim3(256), 0, stream,
                     (const float4*)qkv_w, (ushort4*)wb, 12582912 / 4);
  hipLaunchKernelGGL(k_gemm, dim3(256), dim3(512), 0, stream, xb, wb, qkv_b, qkv);
  hipLaunchKernelGGL(k_normrope, dim3(16384), dim3(256), 0, stream,
                     qkv, q_norm_w, k_norm_w, rot, Qb, Kb, Vb);
  hipLaunchKernelGGL(k_transpose, dim3(2, 32, 32), dim3(256), 0, stream, Vb, Vtb);
  hipLaunchKernelGGL(k_attn, dim3(16, 32), dim3(512), 0, stream, Qb, Kb, Vtb, out);
}

// Round 8
// 260.522 us; speedup vs baseline: 4.2555x; 1.1678x over previous
//
#include <hip/hip_runtime.h>
#include <cstdint>
#include <cstddef>

// ---------------------------------------------------------------------------
// SelfAttention (Flux-style): qkv GEMM + bias -> split q,k,v -> RMSNorm(q,k)
// -> RoPE(q,k) -> flash attention -> out [b,n,dim] fp32.
// b=2, n=2048, dim=2048, h=16, d=128. All MFMA work in bf16 (16x16x32).
//
// R1: XOR-swizzle k_attn LDS (conflicts 1.2e8 -> 1.3e7, attn 347->162us).
// R2: attn VALU diet (fold scale into Q, cvt_pk P-pack, defer-max) + dbuf.
// R3: k_gemm 256x256 ring-4 + counted vmcnt(8) (143us, VGPR 100, no spill).
// R4: k_attn 8 waves/block, QBLK=128, 16 waves/CU (attn out of top-5).
// R5: k_gemm phase-split: NULL. R6: (512,4) reg-cap -> spill (970us), but
//     swizzle f(row)=(row>>1)&3 verified conflict-free (PMC=0).
// R7: 256x384 tile: per-wave 128x96 = 320 regs/thread > 256 cap -> spill
//     (WRITE 107MB, 173us). Lesson: per-wave tile is register-capped at
//     ~128x64; levers left are makespan + conflicts.
// R8: R3 skeleton, retiled BM=128 x BN=384 -> grid 32x16 = 512 blocks =
//     TWO exactly-full passes (was 384 = 75% util). Per wave 64x96 out:
//     acc[4][6] = 96 AGPR (~200 total regs, no spill). 4 gl16/thread/step
//     (1 round A + 3 rounds B) -> same vmcnt(8)/4/0 ladder as R3.
//     Conflict-free swizzle kept on both sides.
// ---------------------------------------------------------------------------

#define LOG2E 1.4426950408889634f
#define ATT_SCALE 0.08838834764831845f   // 1/sqrt(128)
#define QSCALE (ATT_SCALE * LOG2E)       // folded into Q at normrope

typedef __attribute__((ext_vector_type(8))) __bf16 bf16x8;
typedef __attribute__((ext_vector_type(4))) __bf16 bf16x4;
typedef __attribute__((ext_vector_type(4))) float f32x4;

__device__ __forceinline__ float b2f(unsigned u) {
  u <<= 16;
  return __builtin_bit_cast(float, u);
}
__device__ __forceinline__ unsigned short f2b(float f) {
  unsigned x = __builtin_bit_cast(unsigned, f);
  return (unsigned short)((x + 0x7fffu + ((x >> 16) & 1u)) >> 16);  // RNE
}
// async global->LDS, 16B per lane; lds dest must be wave-uniform base (+lane*16)
__device__ __forceinline__ void gl16(const void* g, void* l) {
  __builtin_amdgcn_global_load_lds((__attribute__((address_space(1))) void*)(g),
                                   (__attribute__((address_space(3))) void*)(l), 16, 0, 0);
}

// ---------------- fp32 -> bf16 convert ----------------
__global__ void k_cvt(const float4* __restrict__ in, ushort4* __restrict__ out, int n4) {
  int i = blockIdx.x * blockDim.x + threadIdx.x;
  int st = gridDim.x * blockDim.x;
  for (; i < n4; i += st) {
    float4 v = in[i];
    ushort4 o;
    o.x = f2b(v.x); o.y = f2b(v.y); o.z = f2b(v.z); o.w = f2b(v.w);
    out[i] = o;
  }
}

// ---------------- QKV GEMM: C[4096][6144] = A[4096][2048] * W[6144][2048]^T + bias ----
// 128x384 tile, BK=32, 512 threads = 8 waves (2M x 4N); wave = 64x96 out
// (4x6 frags of 16x16x32, 24 MFMA/step, acc = 96 AGPR). Grid 32x16 = 512
// blocks = 2 exactly-full passes at 1 block/CU. Ring-4 LDS slots of 32KB
// (A 8KB + B 24KB) = 128KB; stage(t+3) while computing t; counted vmcnt(8).
// Swizzle slot ^= (row>>1)&3: conflict-free (R6-verified, PMC=0).
__global__ __launch_bounds__(512, 2) void k_gemm(const unsigned short* __restrict__ A,
                                                 const unsigned short* __restrict__ W,
                                                 const float* __restrict__ bias,
                                                 unsigned short* __restrict__ C) {
  __shared__ __align__(16) unsigned short lds[65536];  // 128KB: 4 x (A[128][32] + B[384][32])
  const int tid = threadIdx.x;
  const int w = tid >> 6, l = tid & 63;
  const int lo = l & 15, hi = l >> 4;
  const int WM = w >> 2, WN = w & 3;
  // bijective XCD swizzle: 512 wgs = 8 XCDs x 64
  const int wg = blockIdx.x;
  const int swz = (wg & 7) * 64 + (wg >> 3);
  const int mbase = (swz >> 4) * 128, nbase = (swz & 15) * 384;

  // staging: per gl16 round 512 threads cover 128 rows x 64B. A = 1 round,
  // B = 3 rounds (4 gl16/thread/step). Source col pre-swizzled; LDS linear.
  const int srow = w * 16 + (l >> 2);                        // row in 128-row round
  const int scol = ((l & 3) * 8) ^ (((srow >> 1) & 3) << 3); // involution per row

  auto stage = [&](int t, int slot) {
    unsigned short* Sa = lds + slot * 16384;   // 32KB slot
    unsigned short* Sb = Sa + 4096;            // A = 8KB
    const int kt = t * 32;
    gl16(A + (size_t)(mbase + srow) * 2048 + kt + scol,
         Sa + (w * 16) * 32);
#pragma unroll
    for (int rd = 0; rd < 3; ++rd)
      gl16(W + (size_t)(nbase + rd * 128 + srow) * 2048 + kt + scol,
           Sb + (rd * 128 + w * 16) * 32);
  };

  f32x4 acc[4][6] = {};
  stage(0, 0); stage(1, 1); stage(2, 2);   // 12 gl16 in flight

  // read-side swizzled element offset: row terms (WM*64, WN*96, i*16) are
  // multiples of 16, so (row>>1)&3 == (lo>>1)&3.
  const int ea = (hi * 8) ^ (((lo >> 1) & 3) << 3);
  for (int t = 0; t < 64; ++t) {
    // lgkmcnt(0)+barrier: all waves' reads of slot t-1 complete => staging
    // slot (t+3)&3 == (t-1)&3 after the barrier is race-free. vmcnt(8):
    // drain slot-t's 4 loads (issued at t-3); 8 newer stay in flight.
    if (t < 62)       asm volatile("s_waitcnt vmcnt(8) lgkmcnt(0)" ::: "memory");
    else if (t == 62) asm volatile("s_waitcnt vmcnt(4) lgkmcnt(0)" ::: "memory");
    else              asm volatile("s_waitcnt vmcnt(0) lgkmcnt(0)" ::: "memory");
    __builtin_amdgcn_sched_barrier(0);
    __builtin_amdgcn_s_barrier();
    __builtin_amdgcn_sched_barrier(0);
    if (t + 3 < 64) stage(t + 3, (t + 3) & 3);

    const unsigned short* Sa = lds + (t & 3) * 16384;
    const unsigned short* Sb = Sa + 4096;
    bf16x8 af[4], bf[6];
#pragma unroll
    for (int i = 0; i < 4; ++i)
      af[i] = *(const bf16x8*)&Sa[(WM * 64 + i * 16 + lo) * 32 + ea];
#pragma unroll
    for (int j = 0; j < 6; ++j)
      bf[j] = *(const bf16x8*)&Sb[(WN * 96 + j * 16 + lo) * 32 + ea];

    __builtin_amdgcn_s_setprio(1);
#pragma unroll
    for (int i = 0; i < 4; ++i)
#pragma unroll
      for (int j = 0; j < 6; ++j)
        acc[i][j] = __builtin_amdgcn_mfma_f32_16x16x32_bf16(af[i], bf[j], acc[i][j], 0, 0, 0);
    __builtin_amdgcn_s_setprio(0);
  }

  const int rowb = mbase + WM * 64;
  const int colb = nbase + WN * 96;
#pragma unroll
  for (int j = 0; j < 6; ++j) {
    float bj = bias[colb + j * 16 + lo];
#pragma unroll
    for (int i = 0; i < 4; ++i)
#pragma unroll
      for (int r = 0; r < 4; ++r) {
        int row = rowb + i * 16 + hi * 4 + r;  // C/D: col=lane&15, row=(lane>>4)*4+reg
        C[(size_t)row * 6144 + colb + j * 16 + lo] = f2b(acc[i][j][r] + bj);
      }
  }
}

// ---------------- RMSNorm + RoPE + split ----------------
// qkv[t][o] bf16, o = h*384 + dd*3 + j (j in {q,k,v}). One wave per (b,n,h),
// 4 waves per block; lane handles pair dd = 2l, 2l+1. Writes Q,K,V in
// [b*h][n][128] bf16. Q pre-scaled by ATT_SCALE*LOG2E.
__global__ __launch_bounds__(256) void k_normrope(const unsigned short* __restrict__ qkv,
                                                  const float* __restrict__ qw,
                                                  const float* __restrict__ kw,
                                                  const float* __restrict__ rot,
                                                  unsigned short* __restrict__ Q,
                                                  unsigned short* __restrict__ K,
                                                  unsigned short* __restrict__ V) {
  const int l = threadIdx.x & 63;
  const int idx = blockIdx.x * 4 + (threadIdx.x >> 6);
  const int h = idx & 15;
  const int n = (idx >> 4) & 2047;
  const int b = idx >> 15;
  const unsigned* p = (const unsigned*)(qkv + (size_t)(b * 2048 + n) * 6144 + h * 384 + l * 6);
  unsigned u0 = p[0], u1 = p[1], u2 = p[2];
  float q0 = b2f(u0 & 0xffff), k0 = b2f(u0 >> 16);
  float v0 = b2f(u1 & 0xffff), q1 = b2f(u1 >> 16);
  float k1 = b2f(u2 & 0xffff), v1 = b2f(u2 >> 16);
  (void)v0; (void)v1;
  float sq = q0 * q0 + q1 * q1, sk = k0 * k0 + k1 * k1;
#pragma unroll
  for (int m = 1; m < 64; m <<= 1) {
    sq += __shfl_xor(sq, m, 64);
    sk += __shfl_xor(sk, m, 64);
  }
  float qi = rsqrtf(sq * (1.0f / 128.0f) + 1e-6f) * QSCALE;  // softmax scale folded in
  float ki = rsqrtf(sk * (1.0f / 128.0f) + 1e-6f);
  float2 qwv = *(const float2*)&qw[2 * l];
  float2 kwv = *(const float2*)&kw[2 * l];
  float4 r = *(const float4*)&rot[n * 256 + l * 4];  // [cos, -sin, sin, cos]
  float qn0 = q0 * qi * qwv.x, qn1 = q1 * qi * qwv.y;
  float kn0 = k0 * ki * kwv.x, kn1 = k1 * ki * kwv.y;
  unsigned qo = (unsigned)f2b(r.x * qn0 + r.y * qn1) | ((unsigned)f2b(r.z * qn0 + r.w * qn1) << 16);
  unsigned ko = (unsigned)f2b(r.x * kn0 + r.y * kn1) | ((unsigned)f2b(r.z * kn0 + r.w * kn1) << 16);
  unsigned vo = (u1 & 0xffffu) | (u2 & 0xffff0000u);  // v passthrough (already bf16)
  size_t ob = ((size_t)(b * 16 + h) * 2048 + n) * 128 + 2 * l;
  *(unsigned*)(Q + ob) = qo;
  *(unsigned*)(K + ob) = ko;
  *(unsigned*)(V + ob) = vo;
}

// ---------------- V transpose: [bh][n][128] -> [bh][128][n] ----------------
__global__ __launch_bounds__(256) void k_transpose(const unsigned short* __restrict__ V,
                                                   unsigned short* __restrict__ Vt) {
  __shared__ unsigned short tile[64 * 66];
  const int t = threadIdx.x;
  const int d0 = blockIdx.x * 64;
  const int n0 = blockIdx.y * 64;
  const int bh = blockIdx.z;
#pragma unroll
  for (int s = t; s < 512; s += 256) {
    int nr = s >> 3, c8 = (s & 7) * 8;
    uint4 vv = *(const uint4*)(V + ((size_t)bh * 2048 + n0 + nr) * 128 + d0 + c8);
    unsigned* tp = (unsigned*)&tile[nr * 66 + c8];
    tp[0] = vv.x; tp[1] = vv.y; tp[2] = vv.z; tp[3] = vv.w;
  }
  __syncthreads();
#pragma unroll
  for (int s = t; s < 512; s += 256) {
    int dr = s >> 3, n8 = (s & 7) * 8;
    unsigned short e[8];
#pragma unroll
    for (int j = 0; j < 8; ++j) e[j] = tile[(n8 + j) * 66 + dr];
    uint4 o;
    o.x = e[0] | ((unsigned)e[1] << 16);
    o.y = e[2] | ((unsigned)e[3] << 16);
    o.z = e[4] | ((unsigned)e[5] << 16);
    o.w = e[6] | ((unsigned)e[7] << 16);
    *(uint4*)(Vt + ((size_t)bh * 128 + d0 + dr) * 2048 + n0 + n8) = o;
  }
}

// ---------------- flash attention ----------------
// R4: 8 waves (512 thr), each owns 16 q-rows (QBLK=128). KV tiles of 64,
// double-buffered, staged cooperatively by all 8 waves (4 gl16/thread).
// S^T = K*Q^T (D row=kv, col=q) so row stats reduce via shfl_xor(16,32);
// P^T written to per-wave LDS as Ps[q][kv]; O^T = V^T * P^T in 8 frags.
// All LDS tiles XOR-swizzled: element_off_in_row ^= ((row & 7) << 3).
// Q arrives pre-scaled by ATT_SCALE*LOG2E, so S is already in log2 units.
// LDS = 2*(16KB K + 16KB Vt) + 8*2KB Ps = 80KB -> 2 blocks/CU, 16 waves/CU.
__global__ __launch_bounds__(512, 4) void k_attn(const unsigned short* __restrict__ Q,
                                                 const unsigned short* __restrict__ K,
                                                 const unsigned short* __restrict__ Vt,
                                                 float* __restrict__ out) {
  __shared__ __align__(16) unsigned short lds[40960];  // 80KB
  unsigned short* Ps = lds + 32768;                    // 8 waves x [16][64]
  const int tid = threadIdx.x;
  const int w = tid >> 6, l = tid & 63;
  const int lo = l & 15, hi = l >> 4;
  const int swz = (lo & 7) << 3;       // read-side XOR for row = ...+lo tiles
  const int qt = blockIdx.x, bh = blockIdx.y;
  const unsigned short* Qb = Q + (size_t)bh * 2048 * 128;
  const unsigned short* Kb = K + (size_t)bh * 2048 * 128;
  const unsigned short* Vb = Vt + (size_t)bh * 128 * 2048;
  unsigned short* Psw = Ps + w * 1024;

  bf16x8 qf[4];
  const int qrow = qt * 128 + w * 16 + lo;
#pragma unroll
  for (int dk = 0; dk < 4; ++dk)
    qf[dk] = *(const bf16x8*)&Qb[(size_t)qrow * 128 + dk * 32 + hi * 8];

  f32x4 Oacc[8] = {};
  float m_run = -__builtin_inff(), l_run = 0.0f;

  // Running per-thread source pointers. Swizzle XOR constants are
  // tile-invariant: tile (t*64) and round (r*32 / r*64) row offsets are
  // multiples of 8, so row&7 depends only on the per-thread base row.
  const int krow0 = w * 4 + hi;             // K row within 32-row round
  const int vrow0 = w * 8 + (l >> 3);       // Vt row within 64-row round
  const unsigned short* kp = Kb + (size_t)krow0 * 128 + ((lo * 8) ^ ((krow0 & 7) << 3));
  const unsigned short* vp = Vb + (size_t)vrow0 * 2048 + (((l & 7) * 8) ^ ((vrow0 & 7) << 3));

  // stage KV tile t into buffer b: K[64][128] in 2 rounds of 32 rows,
  // Vt[128->covered 64 cols][...] i.e. Vts[128][64] in 2 rounds of 64 rows.
  auto stage = [&](int t, int b) {
    unsigned short* Ksb = lds + b * 16384;
    unsigned short* Vtsb = Ksb + 8192;
#pragma unroll
    for (int r = 0; r < 2; ++r) {
      gl16(kp + (size_t)t * 8192 + r * 4096,            // 64*128 per tile, 32*128 per round
           Ksb + (r * 32 + w * 4) * 128);
      gl16(vp + (size_t)r * 131072 + t * 64,            // 64 rows * 2048 per round
           Vtsb + (r * 64 + w * 8) * 64);
    }
  };

  stage(0, 0);
  int cur = 0;
  for (int t = 0; t < 32; ++t) {
    // __syncthreads drains vmcnt(0)+lgkmcnt(0): the stage issued last
    // iteration has had a full compute phase of slack before this wait,
    // and all waves' reads of buffer cur^1 (iter t-1) are complete.
    __syncthreads();
    if (t + 1 < 32) stage(t + 1, cur ^ 1);
    const unsigned short* Ks = lds + cur * 16384;
    const unsigned short* Vts = Ks + 8192;

    f32x4 S[4] = {};
#pragma unroll
    for (int kf = 0; kf < 4; ++kf)
#pragma unroll
      for (int dk = 0; dk < 4; ++dk)
        S[kf] = __builtin_amdgcn_mfma_f32_16x16x32_bf16(
            *(const bf16x8*)&Ks[(kf * 16 + lo) * 128 + ((dk * 32 + hi * 8) ^ swz)],
            qf[dk], S[kf], 0, 0, 0);

    // row max (tree; S already in log2 units)
    float m01, m23, mt;
    m01 = fmaxf(fmaxf(S[0][0], S[0][1]), fmaxf(S[0][2], S[0][3]));
    m23 = fmaxf(fmaxf(S[1][0], S[1][1]), fmaxf(S[1][2], S[1][3]));
    mt = fmaxf(m01, m23);
    m01 = fmaxf(fmaxf(S[2][0], S[2][1]), fmaxf(S[2][2], S[2][3]));
    m23 = fmaxf(fmaxf(S[3][0], S[3][1]), fmaxf(S[3][2], S[3][3]));
    mt = fmaxf(mt, fmaxf(m01, m23));
    mt = fmaxf(mt, __shfl_xor(mt, 16, 64));
    mt = fmaxf(mt, __shfl_xor(mt, 32, 64));

    // T13 defer-max: skip rescale when the new tile max is within 8 of the
    // running max (P bounded by 2^8; f32 accum has headroom).
    const bool defer = __all(mt <= m_run + 8.0f);
    float m_new = m_run, alpha = 1.0f;
    if (!defer) {
      m_new = fmaxf(m_run, mt);
      alpha = exp2f(m_run - m_new);
    }

    float p[4][4];
    float ls = 0.0f;
#pragma unroll
    for (int kf = 0; kf < 4; ++kf)
#pragma unroll
      for (int r = 0; r < 4; ++r) {
        p[kf][r] = exp2f(S[kf][r] - m_new);
        ls += p[kf][r];
      }
    ls += __shfl_xor(ls, 16, 64);
    ls += __shfl_xor(ls, 32, 64);

    // pack P to bf16 via compiler casts (v_cvt_pk_bf16_f32)
#pragma unroll
    for (int kf = 0; kf < 4; ++kf) {
      bf16x4 pk;
      pk[0] = (__bf16)p[kf][0]; pk[1] = (__bf16)p[kf][1];
      pk[2] = (__bf16)p[kf][2]; pk[3] = (__bf16)p[kf][3];
      // Ps[q=lo][kv=kf*16+hi*4 .. +3], swizzled by row q (same-wave buffer).
      *(bf16x4*)&Psw[lo * 64 + ((kf * 16 + hi * 4) ^ swz)] = pk;
    }

    if (!defer) {
#pragma unroll
      for (int df = 0; df < 8; ++df) {
        Oacc[df][0] *= alpha; Oacc[df][1] *= alpha;
        Oacc[df][2] *= alpha; Oacc[df][3] *= alpha;
      }
      l_run = l_run * alpha + ls;
      m_run = m_new;
    } else {
      l_run += ls;
    }

    const bf16x8 pb0 = *(const bf16x8*)&Psw[lo * 64 + ((hi * 8) ^ swz)];
    const bf16x8 pb1 = *(const bf16x8*)&Psw[lo * 64 + ((32 + hi * 8) ^ swz)];
#pragma unroll
    for (int df = 0; df < 8; ++df) {
      Oacc[df] = __builtin_amdgcn_mfma_f32_16x16x32_bf16(
          *(const bf16x8*)&Vts[(df * 16 + lo) * 64 + ((hi * 8) ^ swz)], pb0, Oacc[df], 0, 0, 0);
      Oacc[df] = __builtin_amdgcn_mfma_f32_16x16x32_bf16(
          *(const bf16x8*)&Vts[(df * 16 + lo) * 64 + ((32 + hi * 8) ^ swz)], pb1, Oacc[df], 0, 0, 0);
    }
    cur ^= 1;
  }

  const float inv = 1.0f / l_run;  // valid for q = lo (replicated across hi groups)
  __syncthreads();                 // done with K/V bufs; reuse as fp32 O staging
  float* Ot = ((float*)lds) + w * 2048;  // [16 q][128 dv] per wave (8x8KB = 64KB)
#pragma unroll
  for (int df = 0; df < 8; ++df)
#pragma unroll
    for (int r = 0; r < 4; ++r)
      Ot[lo * 128 + df * 16 + hi * 4 + r] = Oacc[df][r] * inv;
  const int b = bh >> 4, h = bh & 15;
  const int q2 = l >> 2, c = (l & 3) * 32;
  float* op = out + ((size_t)(b * 2048 + qt * 128 + w * 16 + q2) * 2048 + h * 128 + c);
#pragma unroll
  for (int u = 0; u < 8; ++u)
    *(float4*)&op[u * 4] = *(const float4*)&Ot[q2 * 128 + c + u * 4];
}

// ---------------------------------------------------------------------------
extern "C" void kernel_launch(void* const* d_in, const int* in_sizes, int n_in,
                              void* d_out, int out_size, void* d_ws, size_t ws_size,
                              hipStream_t stream) {
  (void)in_sizes; (void)n_in; (void)out_size; (void)ws_size;
  const float* x = (const float*)d_in[0];
  const float* qkv_w = (const float*)d_in[1];
  const float* qkv_b = (const float*)d_in[2];
  const float* q_norm_w = (const float*)d_in[3];
  const float* k_norm_w = (const float*)d_in[4];
  const float* rot = (const float*)d_in[5];
  float* out = (float*)d_out;
  char* ws = (char*)d_ws;
  // ws layout (bytes): xb 16MB | wb 24MB | qkv 48MB | Q 16MB | K 16MB | V 16MB
  // Vt aliases xb region (dead after GEMM). Total required: ~136 MiB.
  unsigned short* xb  = (unsigned short*)(ws);
  unsigned short* wb  = (unsigned short*)(ws + 16777216);
  unsigned short* qkv = (unsigned short*)(ws + 41943040);
  unsigned short* Qb  = (unsigned short*)(ws + 92274688);
  unsigned short* Kb  = (unsigned short*)(ws + 109051904);
  unsigned short* Vb  = (unsigned short*)(ws + 125829120);
  unsigned short* Vtb = (unsigned short*)(ws);  // alias

  hipLaunchKernelGGL(k_cvt, dim3(1024), dim3(256), 0, stream,
                     (const float4*)x, (ushort4*)xb, 8388608 / 4);
  hipLaunchKernelGGL(k_cvt, dim3(1024), dim3(256), 0, stream,
                     (const float4*)qkv_w, (ushort4*)wb, 12582912 / 4);
  hipLaunchKernelGGL(k_gemm, dim3(512), dim3(512), 0, stream, xb, wb, qkv_b, qkv);
  hipLaunchKernelGGL(k_normrope, dim3(16384), dim3(256), 0, stream,
                     qkv, q_norm_w, k_norm_w, rot, Qb, Kb, Vb);
  hipLaunchKernelGGL(k_transpose, dim3(2, 32, 32), dim3(256), 0, stream, Vb, Vtb);
  hipLaunchKernelGGL(k_attn, dim3(16, 32), dim3(512), 0, stream, Qb, Kb, Vtb, out);
}